// Round 12
// baseline (442.350 us; speedup 1.0000x reference)
//
#include <hip/hip_runtime.h>

#define N_IN 256
#define N_OUT 64
#define NEG_SLOPE 0.01f

typedef __attribute__((ext_vector_type(8))) short short8v;   // 8 bf16
typedef __attribute__((ext_vector_type(4))) float float4v;   // MFMA acc

__device__ inline short f32_to_bf16_rtne(float f) {
    unsigned u = __float_as_uint(f);
    unsigned r = (u + 0x7FFFu + ((u >> 16) & 1u)) >> 16;
    return (short)r;
}

// ---------------------------------------------------------------------------
// Kernel 1: z = h @ W.T via bf16 MFMA, fused logits s_node/d_node.
// ---------------------------------------------------------------------------
constexpr int GM = 64;
constexpr int KP = 264;   // padded K (bf16 units); 528 B row stride, 16B-aligned

__global__ __launch_bounds__(256) void gemm_zsd_mfma(
    const float* __restrict__ h, const float* __restrict__ W,
    const float* __restrict__ A,
    float* __restrict__ z, float* __restrict__ s_node, float* __restrict__ d_node,
    int n_nodes)
{
    __shared__ short hA[GM * KP];
    __shared__ short wB[N_OUT * KP];
    const int t = threadIdx.x;
    const int row0 = blockIdx.x * GM;

    // ---- stage h tile and W, f32 -> bf16(RTNE), 8 cols (16B) per write ----
    for (int j = 0; j < 8; ++j) {
        const int f  = j * 256 + t;      // 8-col group index
        const int r  = f >> 5;           // row 0..63
        const int c8 = f & 31;           // 8-col group 0..31

        int grow = row0 + r;
        if (grow >= n_nodes) grow = n_nodes - 1;   // clamp (tail block)
        const float4* ph = reinterpret_cast<const float4*>(h + (size_t)grow * N_IN + c8 * 8);
        float4 h0 = ph[0], h1 = ph[1];
        short8v pkh;
        pkh[0] = f32_to_bf16_rtne(h0.x); pkh[1] = f32_to_bf16_rtne(h0.y);
        pkh[2] = f32_to_bf16_rtne(h0.z); pkh[3] = f32_to_bf16_rtne(h0.w);
        pkh[4] = f32_to_bf16_rtne(h1.x); pkh[5] = f32_to_bf16_rtne(h1.y);
        pkh[6] = f32_to_bf16_rtne(h1.z); pkh[7] = f32_to_bf16_rtne(h1.w);
        *reinterpret_cast<short8v*>(&hA[r * KP + c8 * 8]) = pkh;

        const float4* pw = reinterpret_cast<const float4*>(W + (size_t)r * N_IN + c8 * 8);
        float4 w0 = pw[0], w1 = pw[1];
        short8v pkw;
        pkw[0] = f32_to_bf16_rtne(w0.x); pkw[1] = f32_to_bf16_rtne(w0.y);
        pkw[2] = f32_to_bf16_rtne(w0.z); pkw[3] = f32_to_bf16_rtne(w0.w);
        pkw[4] = f32_to_bf16_rtne(w1.x); pkw[5] = f32_to_bf16_rtne(w1.y);
        pkw[6] = f32_to_bf16_rtne(w1.z); pkw[7] = f32_to_bf16_rtne(w1.w);
        *reinterpret_cast<short8v*>(&wB[r * KP + c8 * 8]) = pkw;
    }
    __syncthreads();

    const int w  = t >> 6;    // wave id
    const int l  = t & 63;
    const int lr = l & 15;    // A row / B col / C col within 16
    const int lk = l >> 4;    // k-group (0..3)

    float4v acc[4] = {{0.f,0.f,0.f,0.f},{0.f,0.f,0.f,0.f},
                      {0.f,0.f,0.f,0.f},{0.f,0.f,0.f,0.f}};

    for (int kk = 0; kk < 8; ++kk) {                 // K-steps of 32
        const int kbase = kk * 32 + lk * 8;
        const short8v a = *reinterpret_cast<const short8v*>(&hA[(w * 16 + lr) * KP + kbase]);
#pragma unroll
        for (int n = 0; n < 4; ++n) {
            const short8v b = *reinterpret_cast<const short8v*>(&wB[(n * 16 + lr) * KP + kbase]);
            acc[n] = __builtin_amdgcn_mfma_f32_16x16x32_bf16(a, b, acc[n], 0, 0, 0);
        }
    }

    // ---- epilogue: write z (f32), fused s/d logits ----
    float as[4], ad[4];
#pragma unroll
    for (int n = 0; n < 4; ++n) {
        as[n] = A[n * 16 + lr];
        ad[n] = A[N_OUT + n * 16 + lr];
    }

    float sv[4] = {0.f,0.f,0.f,0.f}, dv[4] = {0.f,0.f,0.f,0.f};
#pragma unroll
    for (int n = 0; n < 4; ++n) {
#pragma unroll
        for (int r = 0; r < 4; ++r) {
            const float v = acc[n][r];
            const int grow = row0 + w * 16 + lk * 4 + r;
            if (grow < n_nodes) z[(size_t)grow * N_OUT + n * 16 + lr] = v;
            sv[r] = fmaf(v, as[n], sv[r]);
            dv[r] = fmaf(v, ad[n], dv[r]);
        }
    }
    // reduce over the 16 lanes (lr) of each lk-group
#pragma unroll
    for (int off = 1; off < 16; off <<= 1) {
#pragma unroll
        for (int r = 0; r < 4; ++r) {
            sv[r] += __shfl_xor(sv[r], off);
            dv[r] += __shfl_xor(dv[r], off);
        }
    }
    if (lr == 0) {
#pragma unroll
        for (int r = 0; r < 4; ++r) {
            const int grow = row0 + w * 16 + lk * 4 + r;
            if (grow < n_nodes) { s_node[grow] = sv[r]; d_node[grow] = dv[r]; }
        }
    }
}

// ---------------------------------------------------------------------------
// Kernel 2: histogram of dst  (counts must be pre-zeroed)
// ---------------------------------------------------------------------------
__global__ __launch_bounds__(256) void count_dst(
    const int* __restrict__ dst, int* __restrict__ counts, int n_edges)
{
    int i = blockIdx.x * blockDim.x + threadIdx.x;
    const int stride = gridDim.x * blockDim.x;
    for (; i < n_edges; i += stride)
        atomicAdd(&counts[dst[i]], 1);
}

// ---------------------------------------------------------------------------
// Kernel 3a: per-block exclusive scan (in-place) + block totals
// ---------------------------------------------------------------------------
__global__ __launch_bounds__(1024) void scan_block(
    int* __restrict__ data, int* __restrict__ partials, int n)
{
    __shared__ int tmp[1024];
    const int gid = blockIdx.x * 1024 + threadIdx.x;
    const int v = (gid < n) ? data[gid] : 0;
    tmp[threadIdx.x] = v;
    __syncthreads();
    for (int off = 1; off < 1024; off <<= 1) {
        int t = (threadIdx.x >= off) ? tmp[threadIdx.x - off] : 0;
        __syncthreads();
        tmp[threadIdx.x] += t;
        __syncthreads();
    }
    const int incl = tmp[threadIdx.x];
    if (gid < n) data[gid] = incl - v;               // exclusive within block
    if (threadIdx.x == 1023) partials[blockIdx.x] = incl;
}

// Kernel 3b: exclusive scan of block totals (single block, nb <= 128)
__global__ __launch_bounds__(128) void scan_partials(int* __restrict__ partials, int nb)
{
    __shared__ int tmp[128];
    const int v = (threadIdx.x < nb) ? partials[threadIdx.x] : 0;
    tmp[threadIdx.x] = v;
    __syncthreads();
    for (int off = 1; off < 128; off <<= 1) {
        int t = (threadIdx.x >= off) ? tmp[threadIdx.x - off] : 0;
        __syncthreads();
        tmp[threadIdx.x] += t;
        __syncthreads();
    }
    if (threadIdx.x < nb) partials[threadIdx.x] = tmp[threadIdx.x] - v;
}

// Kernel 3c: add scanned block bases -> full exclusive scan (segment starts)
__global__ __launch_bounds__(256) void scan_add_base(
    int* __restrict__ data, const int* __restrict__ partials, int n)
{
    const int gid = blockIdx.x * blockDim.x + threadIdx.x;
    if (gid < n) data[gid] += partials[gid >> 10];
}

// ---------------------------------------------------------------------------
// Kernel 4: scatter src into dst-sorted order. Minimal dependent chain:
// {coalesced load dst -> atomicAdd(cursor[d]) -> 4B store}. p is NOT
// computed here (gather recomputes it; dst==wave there, s_node L2-resident).
// cursor[] starts as segment starts; ends as segment ends.
// ---------------------------------------------------------------------------
__global__ __launch_bounds__(256) void edge_scatter(
    const int* __restrict__ src, const int* __restrict__ dst,
    int* __restrict__ cursor, int* __restrict__ srcsorted, int n_edges)
{
    int i = blockIdx.x * blockDim.x + threadIdx.x;
    const int stride = gridDim.x * blockDim.x;
    for (; i < n_edges; i += stride) {
        const int d = dst[i];
        const int s = src[i];
        const int pos = atomicAdd(&cursor[d], 1);
        srcsorted[pos] = s;
    }
}

// ---------------------------------------------------------------------------
// Kernel 5: one wave per dst node; 16 lanes per edge, 4 edge slots; unroll-4
// keeps 16 z-rows in flight. p recomputed in-place from s_node[s]+d_node[wave]
// (broadcast loads: all 16 lanes of a slot read the same address).
// ---------------------------------------------------------------------------
__global__ __launch_bounds__(256) void gather_accum(
    const int* __restrict__ srcsorted, const int* __restrict__ segend,
    const float* __restrict__ s_node, const float* __restrict__ d_node,
    const float* __restrict__ z, float* __restrict__ out, int n_nodes)
{
    const int wave = (blockIdx.x * 256 + threadIdx.x) >> 6;
    const int lane = threadIdx.x & 63;
    if (wave >= n_nodes) return;
    const int sub = lane >> 4;   // edge slot 0..3
    const int l16 = lane & 15;   // float4 index within row
    const int end   = segend[wave];
    const int start = (wave == 0) ? 0 : segend[wave - 1];
    const float dnw = d_node[wave];

    float ax = 0.f, ay = 0.f, az = 0.f, aw = 0.f, denom = 0.f;
    int i = start + sub;
    for (; i + 12 < end; i += 16) {
        const int s0 = srcsorted[i];
        const int s1 = srcsorted[i + 4];
        const int s2 = srcsorted[i + 8];
        const int s3 = srcsorted[i + 12];
        const float4 z0 = reinterpret_cast<const float4*>(z + (size_t)s0 * N_OUT)[l16];
        const float4 z1 = reinterpret_cast<const float4*>(z + (size_t)s1 * N_OUT)[l16];
        const float4 z2 = reinterpret_cast<const float4*>(z + (size_t)s2 * N_OUT)[l16];
        const float4 z3 = reinterpret_cast<const float4*>(z + (size_t)s3 * N_OUT)[l16];
        float e0 = s_node[s0] + dnw;
        float e1 = s_node[s1] + dnw;
        float e2 = s_node[s2] + dnw;
        float e3 = s_node[s3] + dnw;
        e0 = (e0 >= 0.f) ? e0 : NEG_SLOPE * e0;
        e1 = (e1 >= 0.f) ? e1 : NEG_SLOPE * e1;
        e2 = (e2 >= 0.f) ? e2 : NEG_SLOPE * e2;
        e3 = (e3 >= 0.f) ? e3 : NEG_SLOPE * e3;
        const float p0 = __expf(e0), p1 = __expf(e1);
        const float p2 = __expf(e2), p3 = __expf(e3);
        denom += (p0 + p1) + (p2 + p3);
        ax = fmaf(p0, z0.x, ax); ay = fmaf(p0, z0.y, ay);
        az = fmaf(p0, z0.z, az); aw = fmaf(p0, z0.w, aw);
        ax = fmaf(p1, z1.x, ax); ay = fmaf(p1, z1.y, ay);
        az = fmaf(p1, z1.z, az); aw = fmaf(p1, z1.w, aw);
        ax = fmaf(p2, z2.x, ax); ay = fmaf(p2, z2.y, ay);
        az = fmaf(p2, z2.z, az); aw = fmaf(p2, z2.w, aw);
        ax = fmaf(p3, z3.x, ax); ay = fmaf(p3, z3.y, ay);
        az = fmaf(p3, z3.z, az); aw = fmaf(p3, z3.w, aw);
    }
    for (; i < end; i += 4) {
        const int s0 = srcsorted[i];
        const float4 z0 = reinterpret_cast<const float4*>(z + (size_t)s0 * N_OUT)[l16];
        float e0 = s_node[s0] + dnw;
        e0 = (e0 >= 0.f) ? e0 : NEG_SLOPE * e0;
        const float p0 = __expf(e0);
        denom += p0;
        ax = fmaf(p0, z0.x, ax); ay = fmaf(p0, z0.y, ay);
        az = fmaf(p0, z0.z, az); aw = fmaf(p0, z0.w, aw);
    }
    // reduce across the 4 edge slots (lanes l16, l16+16, l16+32, l16+48)
#pragma unroll
    for (int off = 16; off < 64; off <<= 1) {
        ax += __shfl_xor(ax, off);
        ay += __shfl_xor(ay, off);
        az += __shfl_xor(az, off);
        aw += __shfl_xor(aw, off);
        denom += __shfl_xor(denom, off);
    }
    if (sub == 0) {
        const float inv = (end > start) ? 1.f / denom : 0.f;
        float4 r;
        r.x = ax * inv; r.y = ay * inv; r.z = az * inv; r.w = aw * inv;
        reinterpret_cast<float4*>(out + (size_t)wave * N_OUT)[l16] = r;
    }
}

// ---------------------------------------------------------------------------
extern "C" void kernel_launch(void* const* d_in, const int* in_sizes, int n_in,
                              void* d_out, int out_size, void* d_ws, size_t ws_size,
                              hipStream_t stream) {
    const float* h = (const float*)d_in[0];
    const float* W = (const float*)d_in[1];
    const float* A = (const float*)d_in[2];
    const int* src = (const int*)d_in[3];
    const int* dst = (const int*)d_in[4];
    float* out = (float*)d_out;

    const int n_nodes = in_sizes[0] / N_IN;
    const int n_edges = in_sizes[3];

    // workspace layout
    char* ws = (char*)d_ws;
    float* z      = (float*)ws;                    ws += (size_t)n_nodes * N_OUT * 4;
    float* s_node = (float*)ws;                    ws += (size_t)n_nodes * 4;
    float* d_node = (float*)ws;                    ws += (size_t)n_nodes * 4;
    int*   counts = (int*)ws;                      ws += (size_t)n_nodes * 4;   // -> offsets -> segends
    int*   parts  = (int*)ws;                      ws += 512;
    int*   srcsorted = (int*)ws;                   // n_edges ints

    const int nb_scan = (n_nodes + 1023) / 1024;   // 98 <= 128

    // zero the histogram only (kernel 5 writes every out element)
    hipMemsetAsync(counts, 0, (size_t)n_nodes * sizeof(int), stream);

    // 1) GEMM + logits (bf16 MFMA)
    gemm_zsd_mfma<<<(n_nodes + GM - 1) / GM, 256, 0, stream>>>(h, W, A, z, s_node, d_node, n_nodes);

    // 2) dst histogram
    count_dst<<<1024, 256, 0, stream>>>(dst, counts, n_edges);

    // 3) exclusive scan -> segment starts
    scan_block<<<nb_scan, 1024, 0, stream>>>(counts, parts, n_nodes);
    scan_partials<<<1, 128, 0, stream>>>(parts, nb_scan);
    scan_add_base<<<(n_nodes + 255) / 256, 256, 0, stream>>>(counts, parts, n_nodes);

    // 4) scatter src into dst-sorted order (counts -> segment ends)
    edge_scatter<<<2048, 256, 0, stream>>>(src, dst, counts, srcsorted, n_edges);

    // 5) per-dst register accumulate (recompute p), single write of out
    gather_accum<<<(n_nodes * 64 + 255) / 256, 256, 0, stream>>>(
        srcsorted, counts, s_node, d_node, z, out, n_nodes);
}

// Round 13
// 307.100 us; speedup vs baseline: 1.4404x; 1.4404x over previous
//
#include <hip/hip_runtime.h>

#define N_IN 256
#define N_OUT 64
#define NEG_SLOPE 0.01f
#define BSHIFT 9
#define BSIZE 512      // dsts per bucket
#define MAXBUCK 256    // supports n_nodes <= 131072

typedef __attribute__((ext_vector_type(8))) short short8v;   // 8 bf16
typedef __attribute__((ext_vector_type(4))) float float4v;   // MFMA acc

__device__ inline short f32_to_bf16_rtne(float f) {
    unsigned u = __float_as_uint(f);
    unsigned r = (u + 0x7FFFu + ((u >> 16) & 1u)) >> 16;
    return (short)r;
}

// ---------------------------------------------------------------------------
// Kernel 1: z = h @ W.T via bf16 MFMA, fused logits s_node/d_node. (unchanged)
// ---------------------------------------------------------------------------
constexpr int GM = 64;
constexpr int KP = 264;

__global__ __launch_bounds__(256) void gemm_zsd_mfma(
    const float* __restrict__ h, const float* __restrict__ W,
    const float* __restrict__ A,
    float* __restrict__ z, float* __restrict__ s_node, float* __restrict__ d_node,
    int n_nodes)
{
    __shared__ short hA[GM * KP];
    __shared__ short wB[N_OUT * KP];
    const int t = threadIdx.x;
    const int row0 = blockIdx.x * GM;

    for (int j = 0; j < 8; ++j) {
        const int f  = j * 256 + t;
        const int r  = f >> 5;
        const int c8 = f & 31;

        int grow = row0 + r;
        if (grow >= n_nodes) grow = n_nodes - 1;
        const float4* ph = reinterpret_cast<const float4*>(h + (size_t)grow * N_IN + c8 * 8);
        float4 h0 = ph[0], h1 = ph[1];
        short8v pkh;
        pkh[0] = f32_to_bf16_rtne(h0.x); pkh[1] = f32_to_bf16_rtne(h0.y);
        pkh[2] = f32_to_bf16_rtne(h0.z); pkh[3] = f32_to_bf16_rtne(h0.w);
        pkh[4] = f32_to_bf16_rtne(h1.x); pkh[5] = f32_to_bf16_rtne(h1.y);
        pkh[6] = f32_to_bf16_rtne(h1.z); pkh[7] = f32_to_bf16_rtne(h1.w);
        *reinterpret_cast<short8v*>(&hA[r * KP + c8 * 8]) = pkh;

        const float4* pw = reinterpret_cast<const float4*>(W + (size_t)r * N_IN + c8 * 8);
        float4 w0 = pw[0], w1 = pw[1];
        short8v pkw;
        pkw[0] = f32_to_bf16_rtne(w0.x); pkw[1] = f32_to_bf16_rtne(w0.y);
        pkw[2] = f32_to_bf16_rtne(w0.z); pkw[3] = f32_to_bf16_rtne(w0.w);
        pkw[4] = f32_to_bf16_rtne(w1.x); pkw[5] = f32_to_bf16_rtne(w1.y);
        pkw[6] = f32_to_bf16_rtne(w1.z); pkw[7] = f32_to_bf16_rtne(w1.w);
        *reinterpret_cast<short8v*>(&wB[r * KP + c8 * 8]) = pkw;
    }
    __syncthreads();

    const int w  = t >> 6;
    const int l  = t & 63;
    const int lr = l & 15;
    const int lk = l >> 4;

    float4v acc[4] = {{0.f,0.f,0.f,0.f},{0.f,0.f,0.f,0.f},
                      {0.f,0.f,0.f,0.f},{0.f,0.f,0.f,0.f}};

    for (int kk = 0; kk < 8; ++kk) {
        const int kbase = kk * 32 + lk * 8;
        const short8v a = *reinterpret_cast<const short8v*>(&hA[(w * 16 + lr) * KP + kbase]);
#pragma unroll
        for (int n = 0; n < 4; ++n) {
            const short8v b = *reinterpret_cast<const short8v*>(&wB[(n * 16 + lr) * KP + kbase]);
            acc[n] = __builtin_amdgcn_mfma_f32_16x16x32_bf16(a, b, acc[n], 0, 0, 0);
        }
    }

    float as[4], ad[4];
#pragma unroll
    for (int n = 0; n < 4; ++n) {
        as[n] = A[n * 16 + lr];
        ad[n] = A[N_OUT + n * 16 + lr];
    }

    float sv[4] = {0.f,0.f,0.f,0.f}, dv[4] = {0.f,0.f,0.f,0.f};
#pragma unroll
    for (int n = 0; n < 4; ++n) {
#pragma unroll
        for (int r = 0; r < 4; ++r) {
            const float v = acc[n][r];
            const int grow = row0 + w * 16 + lk * 4 + r;
            if (grow < n_nodes) z[(size_t)grow * N_OUT + n * 16 + lr] = v;
            sv[r] = fmaf(v, as[n], sv[r]);
            dv[r] = fmaf(v, ad[n], dv[r]);
        }
    }
#pragma unroll
    for (int off = 1; off < 16; off <<= 1) {
#pragma unroll
        for (int r = 0; r < 4; ++r) {
            sv[r] += __shfl_xor(sv[r], off);
            dv[r] += __shfl_xor(dv[r], off);
        }
    }
    if (lr == 0) {
#pragma unroll
        for (int r = 0; r < 4; ++r) {
            const int grow = row0 + w * 16 + lk * 4 + r;
            if (grow < n_nodes) { s_node[grow] = sv[r]; d_node[grow] = dv[r]; }
        }
    }
}

// ---------------------------------------------------------------------------
// Kernel 2: bucket histogram of dst>>9 (LDS-aggregated; bcount pre-zeroed)
// ---------------------------------------------------------------------------
__global__ __launch_bounds__(256) void hist_bucket(
    const int* __restrict__ dst, int* __restrict__ bcount, int n_edges)
{
    __shared__ int cnt[MAXBUCK];
    const int t = threadIdx.x;
    for (int i = t; i < MAXBUCK; i += 256) cnt[i] = 0;
    __syncthreads();
    int i = blockIdx.x * 256 + t;
    const int stride = gridDim.x * 256;
    for (; i < n_edges; i += stride)
        atomicAdd(&cnt[dst[i] >> BSHIFT], 1);
    __syncthreads();
    for (int j = t; j < MAXBUCK; j += 256)
        if (cnt[j]) atomicAdd(&bcount[j], cnt[j]);
}

// ---------------------------------------------------------------------------
// Kernel 3: exclusive scan of bucket counts -> bucket_base[0..nbuck],
// and a mutable copy bucket_cursor.
// ---------------------------------------------------------------------------
__global__ __launch_bounds__(256) void scan_buckets(
    const int* __restrict__ bcount, int* __restrict__ bbase,
    int* __restrict__ bcursor, int nbuck, int n_edges)
{
    __shared__ int tmp[256];
    const int t = threadIdx.x;
    const int v = (t < nbuck) ? bcount[t] : 0;
    tmp[t] = v;
    __syncthreads();
    for (int off = 1; off < 256; off <<= 1) {
        int x = (t >= off) ? tmp[t - off] : 0;
        __syncthreads();
        tmp[t] += x;
        __syncthreads();
    }
    if (t < nbuck) {
        const int excl = tmp[t] - v;
        bbase[t] = excl;
        bcursor[t] = excl;
    }
    if (t == 0) bbase[nbuck] = n_edges;
}

// ---------------------------------------------------------------------------
// Kernel 4: bucket scatter. Each block: LDS-count its chunk per bucket,
// reserve a run per bucket (1 global atomic each), then place
// {(dlow<<23)|src, p} at LDS-cursor positions. Writes land in ~24-edge
// block-private runs -> line writers are block-local (kills the 8x
// cross-XCD line writeback amplification of the flat scatter).
// ---------------------------------------------------------------------------
__global__ __launch_bounds__(256) void bucket_scatter(
    const int* __restrict__ src, const int* __restrict__ dst,
    const float* __restrict__ s_node, const float* __restrict__ d_node,
    int* __restrict__ bcursor, int2* __restrict__ ebuf, int n_edges, int nbuck)
{
    __shared__ int cnt[MAXBUCK];
    __shared__ int wcur[MAXBUCK];
    const int t = threadIdx.x;
    const int chunk = (n_edges + gridDim.x - 1) / gridDim.x;
    const int lo = blockIdx.x * chunk;
    const int hi = min(lo + chunk, n_edges);

    for (int i = t; i < MAXBUCK; i += 256) cnt[i] = 0;
    __syncthreads();
    for (int i = lo + t; i < hi; i += 256)
        atomicAdd(&cnt[dst[i] >> BSHIFT], 1);
    __syncthreads();
    for (int i = t; i < nbuck; i += 256)
        wcur[i] = cnt[i] ? atomicAdd(&bcursor[i], cnt[i]) : 0;
    __syncthreads();
    for (int i = lo + t; i < hi; i += 256) {
        const int d = dst[i];
        const int s = src[i];
        float e = s_node[s] + d_node[d];
        e = (e >= 0.f) ? e : NEG_SLOPE * e;
        const float pe = __expf(e);
        const int b = d >> BSHIFT;
        const int pos = atomicAdd(&wcur[b], 1);
        ebuf[pos] = make_int2(((d & (BSIZE - 1)) << 23) | s, __float_as_int(pe));
    }
}

// ---------------------------------------------------------------------------
// Kernel 5: per-bucket binning. One block per bucket: LDS count/scan over
// the 512 dsts of the bucket, write segend (global end offsets), then
// scatter ebuf -> ebuf2 in final dst-sorted order (stripping dlow).
// All writes to a line come from this one block -> no cross-XCD writeback.
// ---------------------------------------------------------------------------
__global__ __launch_bounds__(1024) void bucket_bin(
    const int2* __restrict__ ebuf, const int* __restrict__ bbase,
    int2* __restrict__ ebuf2, int* __restrict__ segend, int n_nodes)
{
    __shared__ int dcnt[BSIZE];
    __shared__ int dscan[BSIZE];
    __shared__ int dcur[BSIZE];
    const int t = threadIdx.x;
    const int b = blockIdx.x;
    const int lo = bbase[b];
    const int hi = bbase[b + 1];

    if (t < BSIZE) dcnt[t] = 0;
    __syncthreads();
    for (int i = lo + t; i < hi; i += 1024)
        atomicAdd(&dcnt[((unsigned)ebuf[i].x) >> 23], 1);
    __syncthreads();
    const int v = (t < BSIZE) ? dcnt[t] : 0;
    if (t < BSIZE) dscan[t] = v;
    __syncthreads();
    for (int off = 1; off < BSIZE; off <<= 1) {
        int x = (t >= off && t < BSIZE) ? dscan[t - off] : 0;
        __syncthreads();
        if (t < BSIZE) dscan[t] += x;
        __syncthreads();
    }
    if (t < BSIZE) {
        const int d = b * BSIZE + t;
        if (d < n_nodes) segend[d] = lo + dscan[t];   // inclusive -> end offset
        dcur[t] = lo + dscan[t] - v;                  // exclusive -> start cursor
    }
    __syncthreads();
    for (int i = lo + t; i < hi; i += 1024) {
        const int2 e = ebuf[i];
        const unsigned x = (unsigned)e.x;
        const int pos = atomicAdd(&dcur[x >> 23], 1);
        ebuf2[pos] = make_int2((int)(x & 0x7FFFFFu), e.y);
    }
}

// ---------------------------------------------------------------------------
// Kernel 6: gather (round-7 measured form): one wave per dst; 16 lanes/edge,
// 4 edge slots, unroll-4 -> 16 z-rows in flight.
// ---------------------------------------------------------------------------
__global__ __launch_bounds__(256) void gather_accum(
    const int2* __restrict__ edges, const int* __restrict__ segend,
    const float* __restrict__ z, float* __restrict__ out, int n_nodes)
{
    const int wave = (blockIdx.x * 256 + threadIdx.x) >> 6;
    const int lane = threadIdx.x & 63;
    if (wave >= n_nodes) return;
    const int sub = lane >> 4;
    const int l16 = lane & 15;
    const int end   = segend[wave];
    const int start = (wave == 0) ? 0 : segend[wave - 1];

    float ax = 0.f, ay = 0.f, az = 0.f, aw = 0.f, denom = 0.f;
    int i = start + sub;
    for (; i + 12 < end; i += 16) {
        const int2 e0 = edges[i];
        const int2 e1 = edges[i + 4];
        const int2 e2 = edges[i + 8];
        const int2 e3 = edges[i + 12];
        const float4 z0 = reinterpret_cast<const float4*>(z + (size_t)e0.x * N_OUT)[l16];
        const float4 z1 = reinterpret_cast<const float4*>(z + (size_t)e1.x * N_OUT)[l16];
        const float4 z2 = reinterpret_cast<const float4*>(z + (size_t)e2.x * N_OUT)[l16];
        const float4 z3 = reinterpret_cast<const float4*>(z + (size_t)e3.x * N_OUT)[l16];
        const float p0 = __int_as_float(e0.y);
        const float p1 = __int_as_float(e1.y);
        const float p2 = __int_as_float(e2.y);
        const float p3 = __int_as_float(e3.y);
        denom += (p0 + p1) + (p2 + p3);
        ax = fmaf(p0, z0.x, ax); ay = fmaf(p0, z0.y, ay);
        az = fmaf(p0, z0.z, az); aw = fmaf(p0, z0.w, aw);
        ax = fmaf(p1, z1.x, ax); ay = fmaf(p1, z1.y, ay);
        az = fmaf(p1, z1.z, az); aw = fmaf(p1, z1.w, aw);
        ax = fmaf(p2, z2.x, ax); ay = fmaf(p2, z2.y, ay);
        az = fmaf(p2, z2.z, az); aw = fmaf(p2, z2.w, aw);
        ax = fmaf(p3, z3.x, ax); ay = fmaf(p3, z3.y, ay);
        az = fmaf(p3, z3.z, az); aw = fmaf(p3, z3.w, aw);
    }
    for (; i < end; i += 4) {
        const int2 e0 = edges[i];
        const float4 z0 = reinterpret_cast<const float4*>(z + (size_t)e0.x * N_OUT)[l16];
        const float p0 = __int_as_float(e0.y);
        denom += p0;
        ax = fmaf(p0, z0.x, ax); ay = fmaf(p0, z0.y, ay);
        az = fmaf(p0, z0.z, az); aw = fmaf(p0, z0.w, aw);
    }
#pragma unroll
    for (int off = 16; off < 64; off <<= 1) {
        ax += __shfl_xor(ax, off);
        ay += __shfl_xor(ay, off);
        az += __shfl_xor(az, off);
        aw += __shfl_xor(aw, off);
        denom += __shfl_xor(denom, off);
    }
    if (sub == 0) {
        const float inv = (end > start) ? 1.f / denom : 0.f;
        float4 r;
        r.x = ax * inv; r.y = ay * inv; r.z = az * inv; r.w = aw * inv;
        reinterpret_cast<float4*>(out + (size_t)wave * N_OUT)[l16] = r;
    }
}

// ---------------------------------------------------------------------------
extern "C" void kernel_launch(void* const* d_in, const int* in_sizes, int n_in,
                              void* d_out, int out_size, void* d_ws, size_t ws_size,
                              hipStream_t stream) {
    const float* h = (const float*)d_in[0];
    const float* W = (const float*)d_in[1];
    const float* A = (const float*)d_in[2];
    const int* src = (const int*)d_in[3];
    const int* dst = (const int*)d_in[4];
    float* out = (float*)d_out;

    const int n_nodes = in_sizes[0] / N_IN;
    const int n_edges = in_sizes[3];
    const int nbuck = (n_nodes + BSIZE - 1) / BSIZE;   // 196

    // workspace layout (8B alignment maintained)
    char* ws = (char*)d_ws;
    float* z       = (float*)ws;  ws += (size_t)n_nodes * N_OUT * 4;
    float* s_node  = (float*)ws;  ws += (size_t)n_nodes * 4;
    float* d_node  = (float*)ws;  ws += (size_t)n_nodes * 4;
    int*   segend  = (int*)ws;    ws += (size_t)n_nodes * 4;
    int*   bcount  = (int*)ws;    ws += MAXBUCK * 4;
    int*   bbase   = (int*)ws;    ws += (MAXBUCK + 2) * 4;
    int*   bcursor = (int*)ws;    ws += MAXBUCK * 4;
    ws = (char*)(((uintptr_t)ws + 15) & ~(uintptr_t)15);
    int2*  ebuf    = (int2*)ws;   ws += (size_t)n_edges * 8;
    int2*  ebuf2   = (int2*)ws;

    hipMemsetAsync(bcount, 0, MAXBUCK * sizeof(int), stream);

    // 1) GEMM + logits
    gemm_zsd_mfma<<<(n_nodes + GM - 1) / GM, 256, 0, stream>>>(h, W, A, z, s_node, d_node, n_nodes);

    // 2) bucket histogram
    hist_bucket<<<256, 256, 0, stream>>>(dst, bcount, n_edges);

    // 3) bucket scan
    scan_buckets<<<1, 256, 0, stream>>>(bcount, bbase, bcursor, nbuck, n_edges);

    // 4) bucket scatter (computes p, packs dlow|src)
    bucket_scatter<<<256, 256, 0, stream>>>(src, dst, s_node, d_node, bcursor, ebuf, n_edges, nbuck);

    // 5) per-bucket bin -> final dst-sorted ebuf2 + segend
    bucket_bin<<<nbuck, 1024, 0, stream>>>(ebuf, bbase, ebuf2, segend, n_nodes);

    // 6) gather
    gather_accum<<<(n_nodes * 64 + 255) / 256, 256, 0, stream>>>(ebuf2, segend, z, out, n_nodes);
}

// Round 14
// 285.405 us; speedup vs baseline: 1.5499x; 1.0760x over previous
//
#include <hip/hip_runtime.h>

#define N_IN 256
#define N_OUT 64
#define NEG_SLOPE 0.01f
#define BSHIFT 9
#define BSIZE 512      // dsts per bucket
#define MAXBUCK 256    // supports n_nodes <= 131072

typedef __attribute__((ext_vector_type(8))) short short8v;   // 8 bf16
typedef __attribute__((ext_vector_type(4))) float float4v;   // MFMA acc

__device__ inline short f32_to_bf16_rtne(float f) {
    unsigned u = __float_as_uint(f);
    unsigned r = (u + 0x7FFFu + ((u >> 16) & 1u)) >> 16;
    return (short)r;
}
__device__ inline float bf16_to_f32(short s) {
    return __uint_as_float(((unsigned)(unsigned short)s) << 16);
}

// ---------------------------------------------------------------------------
// Kernel 1: z = h @ W.T via bf16 MFMA, fused logits s_node/d_node.
// z stored as bf16 (gather reads it; halves gather bytes).
// ---------------------------------------------------------------------------
constexpr int GM = 64;
constexpr int KP = 264;

__global__ __launch_bounds__(256) void gemm_zsd_mfma(
    const float* __restrict__ h, const float* __restrict__ W,
    const float* __restrict__ A,
    unsigned short* __restrict__ zb, float* __restrict__ s_node, float* __restrict__ d_node,
    int n_nodes)
{
    __shared__ short hA[GM * KP];
    __shared__ short wB[N_OUT * KP];
    const int t = threadIdx.x;
    const int row0 = blockIdx.x * GM;

    for (int j = 0; j < 8; ++j) {
        const int f  = j * 256 + t;
        const int r  = f >> 5;
        const int c8 = f & 31;

        int grow = row0 + r;
        if (grow >= n_nodes) grow = n_nodes - 1;
        const float4* ph = reinterpret_cast<const float4*>(h + (size_t)grow * N_IN + c8 * 8);
        float4 h0 = ph[0], h1 = ph[1];
        short8v pkh;
        pkh[0] = f32_to_bf16_rtne(h0.x); pkh[1] = f32_to_bf16_rtne(h0.y);
        pkh[2] = f32_to_bf16_rtne(h0.z); pkh[3] = f32_to_bf16_rtne(h0.w);
        pkh[4] = f32_to_bf16_rtne(h1.x); pkh[5] = f32_to_bf16_rtne(h1.y);
        pkh[6] = f32_to_bf16_rtne(h1.z); pkh[7] = f32_to_bf16_rtne(h1.w);
        *reinterpret_cast<short8v*>(&hA[r * KP + c8 * 8]) = pkh;

        const float4* pw = reinterpret_cast<const float4*>(W + (size_t)r * N_IN + c8 * 8);
        float4 w0 = pw[0], w1 = pw[1];
        short8v pkw;
        pkw[0] = f32_to_bf16_rtne(w0.x); pkw[1] = f32_to_bf16_rtne(w0.y);
        pkw[2] = f32_to_bf16_rtne(w0.z); pkw[3] = f32_to_bf16_rtne(w0.w);
        pkw[4] = f32_to_bf16_rtne(w1.x); pkw[5] = f32_to_bf16_rtne(w1.y);
        pkw[6] = f32_to_bf16_rtne(w1.z); pkw[7] = f32_to_bf16_rtne(w1.w);
        *reinterpret_cast<short8v*>(&wB[r * KP + c8 * 8]) = pkw;
    }
    __syncthreads();

    const int w  = t >> 6;
    const int l  = t & 63;
    const int lr = l & 15;
    const int lk = l >> 4;

    float4v acc[4] = {{0.f,0.f,0.f,0.f},{0.f,0.f,0.f,0.f},
                      {0.f,0.f,0.f,0.f},{0.f,0.f,0.f,0.f}};

    for (int kk = 0; kk < 8; ++kk) {
        const int kbase = kk * 32 + lk * 8;
        const short8v a = *reinterpret_cast<const short8v*>(&hA[(w * 16 + lr) * KP + kbase]);
#pragma unroll
        for (int n = 0; n < 4; ++n) {
            const short8v b = *reinterpret_cast<const short8v*>(&wB[(n * 16 + lr) * KP + kbase]);
            acc[n] = __builtin_amdgcn_mfma_f32_16x16x32_bf16(a, b, acc[n], 0, 0, 0);
        }
    }

    float as[4], ad[4];
#pragma unroll
    for (int n = 0; n < 4; ++n) {
        as[n] = A[n * 16 + lr];
        ad[n] = A[N_OUT + n * 16 + lr];
    }

    float sv[4] = {0.f,0.f,0.f,0.f}, dv[4] = {0.f,0.f,0.f,0.f};
#pragma unroll
    for (int n = 0; n < 4; ++n) {
#pragma unroll
        for (int r = 0; r < 4; ++r) {
            const float v = acc[n][r];
            const int grow = row0 + w * 16 + lk * 4 + r;
            if (grow < n_nodes)
                zb[(size_t)grow * N_OUT + n * 16 + lr] = (unsigned short)f32_to_bf16_rtne(v);
            sv[r] = fmaf(v, as[n], sv[r]);
            dv[r] = fmaf(v, ad[n], dv[r]);
        }
    }
#pragma unroll
    for (int off = 1; off < 16; off <<= 1) {
#pragma unroll
        for (int r = 0; r < 4; ++r) {
            sv[r] += __shfl_xor(sv[r], off);
            dv[r] += __shfl_xor(dv[r], off);
        }
    }
    if (lr == 0) {
#pragma unroll
        for (int r = 0; r < 4; ++r) {
            const int grow = row0 + w * 16 + lk * 4 + r;
            if (grow < n_nodes) { s_node[grow] = sv[r]; d_node[grow] = dv[r]; }
        }
    }
}

// ---------------------------------------------------------------------------
// Kernel 2: bucket histogram of dst>>9 (LDS-aggregated; bcount pre-zeroed)
// ---------------------------------------------------------------------------
__global__ __launch_bounds__(256) void hist_bucket(
    const int* __restrict__ dst, int* __restrict__ bcount, int n_edges)
{
    __shared__ int cnt[MAXBUCK];
    const int t = threadIdx.x;
    for (int i = t; i < MAXBUCK; i += 256) cnt[i] = 0;
    __syncthreads();
    int i = blockIdx.x * 256 + t;
    const int stride = gridDim.x * 256;
    for (; i < n_edges; i += stride)
        atomicAdd(&cnt[dst[i] >> BSHIFT], 1);
    __syncthreads();
    for (int j = t; j < MAXBUCK; j += 256)
        if (cnt[j]) atomicAdd(&bcount[j], cnt[j]);
}

// ---------------------------------------------------------------------------
// Kernel 3: exclusive scan of bucket counts -> bbase[0..nbuck] + cursor copy
// ---------------------------------------------------------------------------
__global__ __launch_bounds__(256) void scan_buckets(
    const int* __restrict__ bcount, int* __restrict__ bbase,
    int* __restrict__ bcursor, int nbuck, int n_edges)
{
    __shared__ int tmp[256];
    const int t = threadIdx.x;
    const int v = (t < nbuck) ? bcount[t] : 0;
    tmp[t] = v;
    __syncthreads();
    for (int off = 1; off < 256; off <<= 1) {
        int x = (t >= off) ? tmp[t - off] : 0;
        __syncthreads();
        tmp[t] += x;
        __syncthreads();
    }
    if (t < nbuck) {
        const int excl = tmp[t] - v;
        bbase[t] = excl;
        bcursor[t] = excl;
    }
    if (t == 0) bbase[nbuck] = n_edges;
}

// ---------------------------------------------------------------------------
// Kernel 4: bucket scatter -> {(dlow<<23)|src, p} in bucket order.
// Block-private runs keep line writers block-local (no cross-XCD writeback).
// ---------------------------------------------------------------------------
__global__ __launch_bounds__(256) void bucket_scatter(
    const int* __restrict__ src, const int* __restrict__ dst,
    const float* __restrict__ s_node, const float* __restrict__ d_node,
    int* __restrict__ bcursor, int2* __restrict__ ebuf, int n_edges, int nbuck)
{
    __shared__ int cnt[MAXBUCK];
    __shared__ int wcur[MAXBUCK];
    const int t = threadIdx.x;
    const int chunk = (n_edges + gridDim.x - 1) / gridDim.x;
    const int lo = blockIdx.x * chunk;
    const int hi = min(lo + chunk, n_edges);

    for (int i = t; i < MAXBUCK; i += 256) cnt[i] = 0;
    __syncthreads();
    for (int i = lo + t; i < hi; i += 256)
        atomicAdd(&cnt[dst[i] >> BSHIFT], 1);
    __syncthreads();
    for (int i = t; i < nbuck; i += 256)
        wcur[i] = cnt[i] ? atomicAdd(&bcursor[i], cnt[i]) : 0;
    __syncthreads();
    for (int i = lo + t; i < hi; i += 256) {
        const int d = dst[i];
        const int s = src[i];
        float e = s_node[s] + d_node[d];
        e = (e >= 0.f) ? e : NEG_SLOPE * e;
        const float pe = __expf(e);
        const int b = d >> BSHIFT;
        const int pos = atomicAdd(&wcur[b], 1);
        ebuf[pos] = make_int2(((d & (BSIZE - 1)) << 23) | s, __float_as_int(pe));
    }
}

// ---------------------------------------------------------------------------
// Kernel 5: per-bucket binning -> final dst-sorted ebuf2 + segend.
// ---------------------------------------------------------------------------
__global__ __launch_bounds__(1024) void bucket_bin(
    const int2* __restrict__ ebuf, const int* __restrict__ bbase,
    int2* __restrict__ ebuf2, int* __restrict__ segend, int n_nodes)
{
    __shared__ int dcnt[BSIZE];
    __shared__ int dscan[BSIZE];
    __shared__ int dcur[BSIZE];
    const int t = threadIdx.x;
    const int b = blockIdx.x;
    const int lo = bbase[b];
    const int hi = bbase[b + 1];

    if (t < BSIZE) dcnt[t] = 0;
    __syncthreads();
    for (int i = lo + t; i < hi; i += 1024)
        atomicAdd(&dcnt[((unsigned)ebuf[i].x) >> 23], 1);
    __syncthreads();
    const int v = (t < BSIZE) ? dcnt[t] : 0;
    if (t < BSIZE) dscan[t] = v;
    __syncthreads();
    for (int off = 1; off < BSIZE; off <<= 1) {
        int x = (t >= off && t < BSIZE) ? dscan[t - off] : 0;
        __syncthreads();
        if (t < BSIZE) dscan[t] += x;
        __syncthreads();
    }
    if (t < BSIZE) {
        const int d = b * BSIZE + t;
        if (d < n_nodes) segend[d] = lo + dscan[t];
        dcur[t] = lo + dscan[t] - v;
    }
    __syncthreads();
    for (int i = lo + t; i < hi; i += 1024) {
        const int2 e = ebuf[i];
        const unsigned x = (unsigned)e.x;
        const int pos = atomicAdd(&dcur[x >> 23], 1);
        ebuf2[pos] = make_int2((int)(x & 0x7FFFFFu), e.y);
    }
}

// ---------------------------------------------------------------------------
// Kernel 6: gather. One wave per dst; 8 lanes/edge (bf16x8 = 16B per lane),
// 8 edge slots, 2x unroll -> 16 z-rows in flight.
// ---------------------------------------------------------------------------
__global__ __launch_bounds__(256) void gather_accum(
    const int2* __restrict__ edges, const int* __restrict__ segend,
    const unsigned short* __restrict__ zb, float* __restrict__ out, int n_nodes)
{
    const int wave = (blockIdx.x * 256 + threadIdx.x) >> 6;
    const int lane = threadIdx.x & 63;
    if (wave >= n_nodes) return;
    const int sub = lane >> 3;   // edge slot 0..7
    const int l8  = lane & 7;    // 8-col group within row
    const int end   = segend[wave];
    const int start = (wave == 0) ? 0 : segend[wave - 1];

    float acc[8] = {0.f,0.f,0.f,0.f,0.f,0.f,0.f,0.f};
    float denom = 0.f;
    int i = start + sub;
    for (; i + 8 < end; i += 16) {
        const int2 e0 = edges[i];
        const int2 e1 = edges[i + 8];
        const short8v z0 = *reinterpret_cast<const short8v*>(zb + (size_t)e0.x * N_OUT + l8 * 8);
        const short8v z1 = *reinterpret_cast<const short8v*>(zb + (size_t)e1.x * N_OUT + l8 * 8);
        const float p0 = __int_as_float(e0.y);
        const float p1 = __int_as_float(e1.y);
        denom += p0 + p1;
#pragma unroll
        for (int j = 0; j < 8; ++j) {
            acc[j] = fmaf(p0, bf16_to_f32(z0[j]), acc[j]);
            acc[j] = fmaf(p1, bf16_to_f32(z1[j]), acc[j]);
        }
    }
    for (; i < end; i += 8) {
        const int2 e0 = edges[i];
        const short8v z0 = *reinterpret_cast<const short8v*>(zb + (size_t)e0.x * N_OUT + l8 * 8);
        const float p0 = __int_as_float(e0.y);
        denom += p0;
#pragma unroll
        for (int j = 0; j < 8; ++j)
            acc[j] = fmaf(p0, bf16_to_f32(z0[j]), acc[j]);
    }
    // reduce across the 8 edge slots
#pragma unroll
    for (int off = 8; off < 64; off <<= 1) {
#pragma unroll
        for (int j = 0; j < 8; ++j)
            acc[j] += __shfl_xor(acc[j], off);
        denom += __shfl_xor(denom, off);
    }
    if (sub == 0) {
        const float inv = (end > start) ? 1.f / denom : 0.f;
        float4 r0, r1;
        r0.x = acc[0] * inv; r0.y = acc[1] * inv; r0.z = acc[2] * inv; r0.w = acc[3] * inv;
        r1.x = acc[4] * inv; r1.y = acc[5] * inv; r1.z = acc[6] * inv; r1.w = acc[7] * inv;
        float4* po = reinterpret_cast<float4*>(out + (size_t)wave * N_OUT + l8 * 8);
        po[0] = r0; po[1] = r1;
    }
}

// ---------------------------------------------------------------------------
extern "C" void kernel_launch(void* const* d_in, const int* in_sizes, int n_in,
                              void* d_out, int out_size, void* d_ws, size_t ws_size,
                              hipStream_t stream) {
    const float* h = (const float*)d_in[0];
    const float* W = (const float*)d_in[1];
    const float* A = (const float*)d_in[2];
    const int* src = (const int*)d_in[3];
    const int* dst = (const int*)d_in[4];
    float* out = (float*)d_out;

    const int n_nodes = in_sizes[0] / N_IN;
    const int n_edges = in_sizes[3];
    const int nbuck = (n_nodes + BSIZE - 1) / BSIZE;   // 196

    // workspace layout (16B alignment maintained)
    char* ws = (char*)d_ws;
    unsigned short* zb = (unsigned short*)ws;  ws += (size_t)n_nodes * N_OUT * 2;
    float* s_node  = (float*)ws;  ws += (size_t)n_nodes * 4;
    float* d_node  = (float*)ws;  ws += (size_t)n_nodes * 4;
    int*   segend  = (int*)ws;    ws += (size_t)n_nodes * 4;
    int*   bcount  = (int*)ws;    ws += MAXBUCK * 4;
    int*   bbase   = (int*)ws;    ws += (MAXBUCK + 2) * 4;
    int*   bcursor = (int*)ws;    ws += MAXBUCK * 4;
    ws = (char*)(((uintptr_t)ws + 15) & ~(uintptr_t)15);
    int2*  ebuf    = (int2*)ws;   ws += (size_t)n_edges * 8;
    int2*  ebuf2   = (int2*)ws;

    hipMemsetAsync(bcount, 0, MAXBUCK * sizeof(int), stream);

    // 1) GEMM + logits (z -> bf16)
    gemm_zsd_mfma<<<(n_nodes + GM - 1) / GM, 256, 0, stream>>>(h, W, A, zb, s_node, d_node, n_nodes);

    // 2) bucket histogram
    hist_bucket<<<256, 256, 0, stream>>>(dst, bcount, n_edges);

    // 3) bucket scan
    scan_buckets<<<1, 256, 0, stream>>>(bcount, bbase, bcursor, nbuck, n_edges);

    // 4) bucket scatter (computes p, packs dlow|src)
    bucket_scatter<<<256, 256, 0, stream>>>(src, dst, s_node, d_node, bcursor, ebuf, n_edges, nbuck);

    // 5) per-bucket bin -> final dst-sorted ebuf2 + segend
    bucket_bin<<<nbuck, 1024, 0, stream>>>(ebuf, bbase, ebuf2, segend, n_nodes);

    // 6) gather (bf16 z)
    gather_accum<<<(n_nodes * 64 + 255) / 256, 256, 0, stream>>>(ebuf2, segend, zb, out, n_nodes);
}